// Round 1
// baseline (198.193 us; speedup 1.0000x reference)
//
#include <hip/hip_runtime.h>

// Warp (flow-shifted bilinear grid sample), channels_last.
// img: [B,H,W,C] f32, flo: [B,H,W,2] f32 -> out: [B,H,W,C] f32
// B=8 H=384 W=512 C=64

constexpr int B = 8, H = 384, W = 512, C = 64;
constexpr long long NPIX = (long long)B * H * W;   // 1,572,864

__global__ __launch_bounds__(256) void warp_bilinear_kernel(
    const float* __restrict__ img,
    const float* __restrict__ flo,
    float* __restrict__ out)
{
    // 16 threads per pixel, 4 channels (float4) each.
    long long tid = (long long)blockIdx.x * blockDim.x + threadIdx.x;
    long long p = tid >> 4;            // pixel index
    int cq = (int)(tid & 15) << 2;     // channel offset (0,4,...,60)
    if (p >= NPIX) return;

    int x_i = (int)(p % W);
    long long yb = p / W;
    int y_i = (int)(yb % H);
    int b   = (int)(yb / H);

    float2 f = *reinterpret_cast<const float2*>(flo + p * 2);
    float x = (float)x_i + f.x;
    float y = (float)y_i + f.y;

    float x0f = floorf(x);
    float y0f = floorf(y);
    float wx = x - x0f;
    float wy = y - y0f;

    int x0 = min(max((int)x0f, 0), W - 1);
    int x1 = min(max((int)x0f + 1, 0), W - 1);
    int y0 = min(max((int)y0f, 0), H - 1);
    int y1 = min(max((int)y0f + 1, 0), H - 1);

    const float* base = img + (long long)b * H * W * C + cq;
    const float4 Ia = *reinterpret_cast<const float4*>(base + ((long long)y0 * W + x0) * C);
    const float4 Ib = *reinterpret_cast<const float4*>(base + ((long long)y1 * W + x0) * C);
    const float4 Ic = *reinterpret_cast<const float4*>(base + ((long long)y0 * W + x1) * C);
    const float4 Id = *reinterpret_cast<const float4*>(base + ((long long)y1 * W + x1) * C);

    float wa = (1.0f - wx) * (1.0f - wy);
    float wb = (1.0f - wx) * wy;
    float wc = wx * (1.0f - wy);
    float wd = wx * wy;

    float4 r;
    r.x = wa * Ia.x + wb * Ib.x + wc * Ic.x + wd * Id.x;
    r.y = wa * Ia.y + wb * Ib.y + wc * Ic.y + wd * Id.y;
    r.z = wa * Ia.z + wb * Ib.z + wc * Ic.z + wd * Id.z;
    r.w = wa * Ia.w + wb * Ib.w + wc * Ic.w + wd * Id.w;

    *reinterpret_cast<float4*>(out + p * C + cq) = r;
}

extern "C" void kernel_launch(void* const* d_in, const int* in_sizes, int n_in,
                              void* d_out, int out_size, void* d_ws, size_t ws_size,
                              hipStream_t stream) {
    const float* img = (const float*)d_in[0];
    const float* flo = (const float*)d_in[1];
    float* out = (float*)d_out;

    long long total_threads = NPIX * 16;     // 16 threads per pixel
    int block = 256;
    long long grid = (total_threads + block - 1) / block;  // 98,304
    warp_bilinear_kernel<<<(int)grid, block, 0, stream>>>(img, flo, out);
}

// Round 2
// 182.237 us; speedup vs baseline: 1.0876x; 1.0876x over previous
//
#include <hip/hip_runtime.h>

// Warp (flow-shifted bilinear grid sample), channels_last.
// img: [B,H,W,C] f32, flo: [B,H,W,2] f32 -> out: [B,H,W,C] f32
// B=8 H=384 W=512 C=64

constexpr int B = 8, H = 384, W = 512, C = 64;

typedef float f4 __attribute__((ext_vector_type(4)));
typedef float f2 __attribute__((ext_vector_type(2)));

// 8 threads per pixel; each thread owns 8 channels as two float4s at +0 and
// +128 bytes, so every load/store instruction is 128B-contiguous per 8-lane
// group. Grid is (W/32, H, B) -> XCD = x-chunk % 8 statically: each XCD's
// tap footprint is two fixed 32-px column bands (+ ~60 px flow halo) ~3 MB,
// which fits the 4 MB per-XCD L2. Output stores are nontemporal so the
// 403 MB write stream doesn't evict the reused img tap lines from L2.
__global__ __launch_bounds__(256) void warp_bilinear_kernel(
    const float* __restrict__ img,
    const float* __restrict__ flo,
    float* __restrict__ out)
{
    int lane = threadIdx.x & 7;          // channel group: channels [4*lane, 4*lane+4) and +32
    int pix  = threadIdx.x >> 3;         // 0..31 pixel within block
    int x_i = blockIdx.x * 32 + pix;
    int y_i = blockIdx.y;
    int b   = blockIdx.z;

    long long p = ((long long)b * H + y_i) * (long long)W + x_i;

    f2 f = __builtin_nontemporal_load(reinterpret_cast<const f2*>(flo + p * 2));
    float x = (float)x_i + f.x;
    float y = (float)y_i + f.y;

    float x0f = floorf(x);
    float y0f = floorf(y);
    float wx = x - x0f;
    float wy = y - y0f;

    int x0 = min(max((int)x0f, 0), W - 1);
    int x1 = min(max((int)x0f + 1, 0), W - 1);
    int y0 = min(max((int)y0f, 0), H - 1);
    int y1 = min(max((int)y0f + 1, 0), H - 1);

    const float* base = img + (long long)b * H * W * C + (lane << 2);
    const float* pa = base + ((long long)y0 * W + x0) * C;
    const float* pb = base + ((long long)y1 * W + x0) * C;
    const float* pc = base + ((long long)y0 * W + x1) * C;
    const float* pd = base + ((long long)y1 * W + x1) * C;

    f4 Ia0 = *reinterpret_cast<const f4*>(pa);
    f4 Ia1 = *reinterpret_cast<const f4*>(pa + 32);
    f4 Ib0 = *reinterpret_cast<const f4*>(pb);
    f4 Ib1 = *reinterpret_cast<const f4*>(pb + 32);
    f4 Ic0 = *reinterpret_cast<const f4*>(pc);
    f4 Ic1 = *reinterpret_cast<const f4*>(pc + 32);
    f4 Id0 = *reinterpret_cast<const f4*>(pd);
    f4 Id1 = *reinterpret_cast<const f4*>(pd + 32);

    float wa = (1.0f - wx) * (1.0f - wy);
    float wb = (1.0f - wx) * wy;
    float wc = wx * (1.0f - wy);
    float wd = wx * wy;

    f4 r0 = wa * Ia0 + wb * Ib0 + wc * Ic0 + wd * Id0;
    f4 r1 = wa * Ia1 + wb * Ib1 + wc * Ic1 + wd * Id1;

    float* op = out + p * C + (lane << 2);
    __builtin_nontemporal_store(r0, reinterpret_cast<f4*>(op));
    __builtin_nontemporal_store(r1, reinterpret_cast<f4*>(op + 32));
}

extern "C" void kernel_launch(void* const* d_in, const int* in_sizes, int n_in,
                              void* d_out, int out_size, void* d_ws, size_t ws_size,
                              hipStream_t stream) {
    const float* img = (const float*)d_in[0];
    const float* flo = (const float*)d_in[1];
    float* out = (float*)d_out;

    dim3 grid(W / 32, H, B);   // 16 x 384 x 8 = 49152 blocks, 32 pixels/block
    dim3 block(256);
    warp_bilinear_kernel<<<grid, block, 0, stream>>>(img, flo, out);
}

// Round 3
// 180.783 us; speedup vs baseline: 1.0963x; 1.0080x over previous
//
#include <hip/hip_runtime.h>

// Warp (flow-shifted bilinear grid sample), channels_last.
// img: [B,H,W,C] f32, flo: [B,H,W,2] f32 -> out: [B,H,W,C] f32
// B=8 H=384 W=512 C=64

constexpr int B = 8, H = 384, W = 512, C = 64;

typedef float f4 __attribute__((ext_vector_type(4)));
typedef float f2 __attribute__((ext_vector_type(2)));

// 8 threads per pixel; each thread owns 8 channels as two float4s at +0 and
// +128 bytes -> every img load is 128B-contiguous per 8-lane group.
// Grid (W/32, H, B); hardware round-robins linear block id across 8 XCDs,
// so XCD = blockIdx.x % 8. The x-chunk swizzle xc = ((bid&7)<<1)|(bid>>3)
// gives XCD k the CONTIGUOUS 64-px band {2k,2k+1} instead of two separated
// bands {k,k+8}: column extent of the tap footprint shrinks 224 -> 144 px,
// improving per-XCD L2 capture of the flow-halo reuse.
// Output stores are nontemporal: the 403 MB write stream must not evict
// img tap lines (each has ~4x reuse) from L2.
__global__ __launch_bounds__(256) void warp_bilinear_kernel(
    const float* __restrict__ img,
    const float* __restrict__ flo,
    float* __restrict__ out)
{
    int lane = threadIdx.x & 7;          // channel group
    int pix  = threadIdx.x >> 3;         // 0..31 pixel within block
    int bidx = blockIdx.x;               // 0..15
    int xc   = ((bidx & 7) << 1) | (bidx >> 3);  // XCD-contiguous band swizzle
    int x_i  = xc * 32 + pix;
    int y_i  = blockIdx.y;
    int b    = blockIdx.z;

    // 32-bit in-batch offsets (per-batch elems: 384*512*64 = 12.6M < 2^31)
    unsigned pin = (unsigned)y_i * W + (unsigned)x_i;      // pixel within batch
    const float* imgb = img + (size_t)b * (H * W * C);
    const float* flob = flo + (size_t)b * (H * W * 2);
    float*       outb = out + (size_t)b * (H * W * C);

    f2 f = __builtin_nontemporal_load(reinterpret_cast<const f2*>(flob + pin * 2u));
    float x = (float)x_i + f.x;
    float y = (float)y_i + f.y;

    float x0f = floorf(x);
    float y0f = floorf(y);
    float wx = x - x0f;
    float wy = y - y0f;

    int x0 = min(max((int)x0f, 0), W - 1);
    int x1 = min(max((int)x0f + 1, 0), W - 1);
    int y0 = min(max((int)y0f, 0), H - 1);
    int y1 = min(max((int)y0f + 1, 0), H - 1);

    unsigned co = (unsigned)(lane << 2);
    unsigned ta = ((unsigned)y0 * W + (unsigned)x0) * C + co;
    unsigned tb = ((unsigned)y1 * W + (unsigned)x0) * C + co;
    unsigned tc = ((unsigned)y0 * W + (unsigned)x1) * C + co;
    unsigned td = ((unsigned)y1 * W + (unsigned)x1) * C + co;

    f4 Ia0 = *reinterpret_cast<const f4*>(imgb + ta);
    f4 Ia1 = *reinterpret_cast<const f4*>(imgb + ta + 32u);
    f4 Ib0 = *reinterpret_cast<const f4*>(imgb + tb);
    f4 Ib1 = *reinterpret_cast<const f4*>(imgb + tb + 32u);
    f4 Ic0 = *reinterpret_cast<const f4*>(imgb + tc);
    f4 Ic1 = *reinterpret_cast<const f4*>(imgb + tc + 32u);
    f4 Id0 = *reinterpret_cast<const f4*>(imgb + td);
    f4 Id1 = *reinterpret_cast<const f4*>(imgb + td + 32u);

    float wa = (1.0f - wx) * (1.0f - wy);
    float wb = (1.0f - wx) * wy;
    float wc = wx * (1.0f - wy);
    float wd = wx * wy;

    f4 r0 = wa * Ia0 + wb * Ib0 + wc * Ic0 + wd * Id0;
    f4 r1 = wa * Ia1 + wb * Ib1 + wc * Ic1 + wd * Id1;

    float* op = outb + pin * C + co;
    __builtin_nontemporal_store(r0, reinterpret_cast<f4*>(op));
    __builtin_nontemporal_store(r1, reinterpret_cast<f4*>(op + 32));
}

extern "C" void kernel_launch(void* const* d_in, const int* in_sizes, int n_in,
                              void* d_out, int out_size, void* d_ws, size_t ws_size,
                              hipStream_t stream) {
    const float* img = (const float*)d_in[0];
    const float* flo = (const float*)d_in[1];
    float* out = (float*)d_out;

    dim3 grid(W / 32, H, B);   // 16 x 384 x 8 = 49152 blocks, 32 pixels/block
    dim3 block(256);
    warp_bilinear_kernel<<<grid, block, 0, stream>>>(img, flo, out);
}